// Round 1
// baseline (692.056 us; speedup 1.0000x reference)
//
#include <hip/hip_runtime.h>
#include <hip/hip_bf16.h>

// Sizes (fixed by the problem)
#define NH   128        // hidden channels H
#define NR   6          // radial
#define NCOL 390        // 3H + 2*SH
#define TILE_E 64       // edges per block
#define LDK  136        // padded LDS row stride (bf16 elems): 128 + 8

typedef __attribute__((ext_vector_type(8))) short bf16x8;   // 8 bf16 in 4 VGPRs
typedef __attribute__((ext_vector_type(4))) float f32x4;

// ---------------------------------------------------------------------------
// Prep 1: combined node tables.
//  Ci[a*3+sc][n] = sum_k emb_w[a][k]*lin_w[n][k]      + sum_c S[sc][c]*lin_w[n][128+c] + lin_b[n]
//  Cj[a*3+sc][n] = sum_k emb_w[a][k]*lin_w[n][131+k]  + sum_c S[sc][c]*lin_w[n][259+c]
//  with S[sc][c] = spin_w[c][sc] + spin_b[c]
// grid = 570 blocks (285 Ci rows, 285 Cj rows), block = 128 threads
// ---------------------------------------------------------------------------
__global__ void prep_tables(const float* __restrict__ emb_w,
                            const float* __restrict__ spin_w,
                            const float* __restrict__ spin_b,
                            const float* __restrict__ lin_w,
                            const float* __restrict__ lin_b,
                            float* __restrict__ Ci, float* __restrict__ Cj) {
    int row = blockIdx.x;            // 0..569
    int n   = threadIdx.x;           // 0..127
    bool isJ = row >= 285;
    int rr = isJ ? row - 285 : row;
    int a  = rr / 3;
    int sc = rr % 3;
    const int col0 = isJ ? 131 : 0;
    const int cols = isJ ? 259 : 128;
    const float* wrow = lin_w + (size_t)n * NCOL;
    float acc = isJ ? 0.0f : lin_b[n];
    #pragma unroll 8
    for (int k = 0; k < NH; ++k)
        acc += emb_w[a * NH + k] * wrow[col0 + k];
    #pragma unroll
    for (int c = 0; c < 3; ++c)
        acc += (spin_w[c * 3 + sc] + spin_b[c]) * wrow[cols + c];
    (isJ ? Cj : Ci)[rr * NH + n] = acc;
}

// ---------------------------------------------------------------------------
// Prep 2: bf16 copy of lin_w[:, 262:390], row-major [n][k].
// grid = 64, block = 256
// ---------------------------------------------------------------------------
__global__ void prep_w(const float* __restrict__ lin_w, __hip_bfloat16* __restrict__ Wb) {
    int idx = blockIdx.x * 256 + threadIdx.x;       // 0..16383
    int n = idx >> 7, k = idx & 127;
    Wb[idx] = __float2bfloat16(lin_w[(size_t)n * NCOL + 262 + k]);
}

// ---------------------------------------------------------------------------
// Main fused kernel: 64 edges/block, 256 threads (4 waves).
// ---------------------------------------------------------------------------
__global__ __launch_bounds__(256, 2) void fused_main(
        const int*   __restrict__ x,   const int* __restrict__ s,
        const float* __restrict__ rbf,
        const int*   __restrict__ gi,  const int* __restrict__ gj,
        const float* __restrict__ rbf_w, const float* __restrict__ rbf_b,
        const float* __restrict__ Ci,  const float* __restrict__ Cj,
        const __hip_bfloat16* __restrict__ Wb,
        float* __restrict__ out, int E) {
    __shared__ __align__(16) __hip_bfloat16 r_lds[TILE_E * LDK];
    __shared__ __align__(16) __hip_bfloat16 w_lds[NH * LDK];
    __shared__ float rbf_lds[TILE_E * NR];
    __shared__ int ci_lds[TILE_E], cj_lds[TILE_E];

    const int tid = threadIdx.x;
    const int e0  = blockIdx.x * TILE_E;

    // ---- stage W (bf16 128x128) into padded LDS: 2048 x 16B chunks ----
    {
        const uint4* src = (const uint4*)Wb;            // 8 bf16 per chunk
        #pragma unroll
        for (int it = 0; it < 8; ++it) {
            int l = it * 256 + tid;                     // 0..2047
            int row = l >> 4, c = l & 15;               // 16 chunks per row
            uint4 v = src[l];
            *(uint4*)&w_lds[row * LDK + c * 8] = v;
        }
    }

    // ---- stage rbf tile: 64*6 = 384 floats = 192 float2 ----
    if (tid < 192) {
        int nvalid = (E - e0 >= TILE_E ? TILE_E : (E - e0)) * NR;   // floats in tile
        float2 v = make_float2(0.f, 0.f);
        if (tid * 2 < nvalid)
            v = ((const float2*)(rbf + (size_t)e0 * NR))[tid];
        ((float2*)rbf_lds)[tid] = v;
    }

    // ---- combined node-class indices for this tile ----
    if (tid < TILE_E) {
        int e = e0 + tid; if (e >= E) e = E - 1;
        int ii = gi[e];
        ci_lds[tid] = x[ii] * 3 + s[ii];
    } else if (tid < 2 * TILE_E) {
        int t = tid - TILE_E;
        int e = e0 + t; if (e >= E) e = E - 1;
        int jj = gj[e];
        cj_lds[t] = x[jj] * 3 + s[jj];
    }
    __syncthreads();

    // ---- r = silu(rbf @ rbf_w^T + rbf_b), bf16 into LDS ----
    // thread layout: k = tid&127 fixed per thread, e sweeps
    {
        int k  = tid & 127;
        int hi = tid >> 7;                  // 0 or 1
        float w0 = rbf_w[k * NR + 0], w1 = rbf_w[k * NR + 1], w2 = rbf_w[k * NR + 2];
        float w3 = rbf_w[k * NR + 3], w4 = rbf_w[k * NR + 4], w5 = rbf_w[k * NR + 5];
        float bb = rbf_b[k];
        #pragma unroll 4
        for (int t = 0; t < 32; ++t) {
            int e = t * 2 + hi;
            const float* re = &rbf_lds[e * NR];
            float acc = bb + re[0] * w0 + re[1] * w1 + re[2] * w2
                           + re[3] * w3 + re[4] * w4 + re[5] * w5;
            float sv = acc / (1.0f + __expf(-acc));
            r_lds[e * LDK + k] = __float2bfloat16(sv);
        }
    }
    __syncthreads();

    // ---- MFMA: each wave does 16 edges x 128 out-channels ----
    const int wave   = tid >> 6;
    const int lane   = tid & 63;
    const int lane15 = lane & 15;
    const int quad   = lane >> 4;
    const int e_sub  = wave * 16;

    // A fragments: A[m=lane&15][k=quad*8+j], r row-major in LDS
    bf16x8 afrag[4];
    #pragma unroll
    for (int kt = 0; kt < 4; ++kt)
        afrag[kt] = *(const bf16x8*)&r_lds[(e_sub + lane15) * LDK + kt * 32 + quad * 8];

    const int e_row = e_sub + quad * 4;     // D row base; +reg
    int cio[4], cjo[4];
    #pragma unroll
    for (int reg = 0; reg < 4; ++reg) {
        cio[reg] = ci_lds[e_row + reg] * NH;
        cjo[reg] = cj_lds[e_row + reg] * NH;
    }

    #pragma unroll
    for (int nt = 0; nt < 8; ++nt) {
        f32x4 acc = {0.f, 0.f, 0.f, 0.f};
        #pragma unroll
        for (int kt = 0; kt < 4; ++kt) {
            bf16x8 bfrag = *(const bf16x8*)&w_lds[(nt * 16 + lane15) * LDK + kt * 32 + quad * 8];
            acc = __builtin_amdgcn_mfma_f32_16x16x32_bf16(afrag[kt], bfrag, acc, 0, 0, 0);
        }
        int n = nt * 16 + lane15;
        #pragma unroll
        for (int reg = 0; reg < 4; ++reg) {
            int eg = e0 + e_row + reg;
            if (eg < E) {
                float base = Ci[cio[reg] + n] + Cj[cjo[reg] + n];
                float v = acc[reg] + base;
                out[(size_t)eg * NH + n] = v / (1.0f + __expf(-v));
            }
        }
    }
}

// ---------------------------------------------------------------------------
extern "C" void kernel_launch(void* const* d_in, const int* in_sizes, int n_in,
                              void* d_out, int out_size, void* d_ws, size_t ws_size,
                              hipStream_t stream) {
    const int*   x      = (const int*)  d_in[0];
    const int*   s      = (const int*)  d_in[1];
    const float* rbf    = (const float*)d_in[2];
    const int*   gi     = (const int*)  d_in[3];
    const int*   gj     = (const int*)  d_in[4];
    const float* emb_w  = (const float*)d_in[5];
    const float* spin_w = (const float*)d_in[6];
    const float* spin_b = (const float*)d_in[7];
    const float* rbf_w  = (const float*)d_in[8];
    const float* rbf_b  = (const float*)d_in[9];
    const float* lin_w  = (const float*)d_in[10];
    const float* lin_b  = (const float*)d_in[11];
    const int E = in_sizes[3];

    float* Ci = (float*)d_ws;                         // 285*128 f32
    float* Cj = Ci + 285 * NH;                        // 285*128 f32
    __hip_bfloat16* Wb = (__hip_bfloat16*)(Cj + 285 * NH);  // 128*128 bf16

    prep_tables<<<570, 128, 0, stream>>>(emb_w, spin_w, spin_b, lin_w, lin_b, Ci, Cj);
    prep_w<<<64, 256, 0, stream>>>(lin_w, Wb);

    int nblk = (E + TILE_E - 1) / TILE_E;
    fused_main<<<nblk, 256, 0, stream>>>(x, s, rbf, gi, gj, rbf_w, rbf_b,
                                         Ci, Cj, Wb, (float*)d_out, E);
}